// Round 1
// baseline (89.234 us; speedup 1.0000x reference)
//
#include <hip/hip_runtime.h>

// Chamfer nearest-neighbor squared distances.
// points1: [B, N, 3] fp32, points2: [B, M, 3] fp32
// out: dist1 [B*N] then dist2 [B*M], fp32.
//
// Strategy: each thread owns IPT=2 query points in registers; reference
// points staged into LDS as float4 (padded) and broadcast-read per j.
// Reference dim split SPLIT ways across blocks for occupancy; partial
// minima combined with atomicMin on the int view (distances >= 0).

constexpr int TPB   = 256;  // threads per block (4 waves)
constexpr int IPT   = 2;    // query points per thread
constexpr int TILE  = 512;  // reference points staged per LDS tile
constexpr int SPLIT = 2;    // reference-dim split factor (occupancy)

__global__ __launch_bounds__(TPB, 2) void nnd_kernel(
    const float* __restrict__ p1, const float* __restrict__ p2,
    float* __restrict__ out, int N, int M)
{
    const int z   = blockIdx.z;
    const int dir = z / SPLIT;   // 0: queries=p1 refs=p2 (dist1); 1: swapped (dist2)
    const int s   = z % SPLIT;
    const int b   = blockIdx.y;
    const int Bc  = gridDim.y;

    const float* __restrict__ q = dir ? p2 : p1;
    const float* __restrict__ r = dir ? p1 : p2;
    const int Nq = dir ? M : N;
    const int Nr = dir ? N : M;
    float* __restrict__ o = out + (dir ? (size_t)Bc * (size_t)N : 0) + (size_t)b * Nq;

    const int t  = threadIdx.x;
    const int q0 = blockIdx.x * (TPB * IPT) + t;
    const int q1 = q0 + TPB;

    const float* qb = q + (size_t)b * Nq * 3;
    float x0 = 0.f, y0 = 0.f, z0 = 0.f, x1 = 0.f, y1 = 0.f, z1 = 0.f;
    if (q0 < Nq) { x0 = qb[q0 * 3 + 0]; y0 = qb[q0 * 3 + 1]; z0 = qb[q0 * 3 + 2]; }
    if (q1 < Nq) { x1 = qb[q1 * 3 + 0]; y1 = qb[q1 * 3 + 1]; z1 = qb[q1 * 3 + 2]; }

    const int per = (Nr + SPLIT - 1) / SPLIT;
    const int r0  = s * per;
    const int r1  = min(Nr, r0 + per);

    __shared__ float4 sh[TILE];
    const float* rb = r + (size_t)b * Nr * 3;

    float m0 = 3.0e38f, m1 = 3.0e38f;

    for (int ts = r0; ts < r1; ts += TILE) {
        const int npts = min(TILE, r1 - ts);
        __syncthreads();  // previous tile fully consumed before overwrite
        if (npts == TILE && ((((size_t)b * Nr + (size_t)ts) * 3) & 1) == 0) {
            // fast path: full tile, float2-aligned source
            const float2* src = (const float2*)(rb + (size_t)ts * 3);
            float2 a = src[3 * t + 0];
            float2 c = src[3 * t + 1];
            float2 e = src[3 * t + 2];
            sh[2 * t + 0] = make_float4(a.x, a.y, c.x, 0.f);
            sh[2 * t + 1] = make_float4(c.y, e.x, e.y, 0.f);
        } else {
            // guarded scalar path; pad with far points (dist -> inf, min-neutral)
            #pragma unroll
            for (int k = 0; k < 2; ++k) {
                int pl = 2 * t + k;
                float4 v = make_float4(1e30f, 1e30f, 1e30f, 0.f);
                if (pl < npts) {
                    const float* pp = rb + (size_t)(ts + pl) * 3;
                    v = make_float4(pp[0], pp[1], pp[2], 0.f);
                }
                sh[pl] = v;
            }
        }
        __syncthreads();

        #pragma unroll 8
        for (int j = 0; j < TILE; ++j) {
            float4 p = sh[j];
            float dx0 = x0 - p.x, dy0 = y0 - p.y, dz0 = z0 - p.z;
            float dx1 = x1 - p.x, dy1 = y1 - p.y, dz1 = z1 - p.z;
            float d0 = dx0 * dx0; d0 = fmaf(dy0, dy0, d0); d0 = fmaf(dz0, dz0, d0);
            float d1 = dx1 * dx1; d1 = fmaf(dy1, dy1, d1); d1 = fmaf(dz1, dz1, d1);
            m0 = fminf(m0, d0);
            m1 = fminf(m1, d1);
        }
    }

    // distances are >= 0, so int ordering == float ordering
    if (q0 < Nq) atomicMin((int*)&o[q0], __float_as_int(m0));
    if (q1 < Nq) atomicMin((int*)&o[q1], __float_as_int(m1));
}

extern "C" void kernel_launch(void* const* d_in, const int* in_sizes, int n_in,
                              void* d_out, int out_size, void* d_ws, size_t ws_size,
                              hipStream_t stream) {
    const float* p1 = (const float*)d_in[0];
    const float* p2 = (const float*)d_in[1];
    float* out = (float*)d_out;

    const int B = 16;
    const int N = in_sizes[0] / (B * 3);
    const int M = in_sizes[1] / (B * 3);

    // init output to large positive float (0x7f7f7f7f ~ 3.39e38) for atomicMin
    hipMemsetAsync(d_out, 0x7f, (size_t)out_size * sizeof(float), stream);

    const int qmax    = (N > M) ? N : M;
    const int qblocks = (qmax + TPB * IPT - 1) / (TPB * IPT);
    dim3 grid(qblocks, B, 2 * SPLIT);
    nnd_kernel<<<grid, TPB, 0, stream>>>(p1, p2, out, N, M);
}